// Round 14
// baseline (50.066 us; speedup 1.0000x reference)
//
#include <hip/hip_runtime.h>
#include <hip/hip_fp8.h>

// InfoNCE/contrastive MVN loss:
// loss = mean_i( LSE_j((p_i.g_j - 0.5|g_j|^2)/nv) - (p_i.g_i - 0.5|g_i|^2)/nv ) * 2nv
// B = 8192, D = 256, fp32 inputs, scalar fp32 output.
// Main kernel: fp8-e4m3 32x32x16 MFMA GEMM fused with online base-2 LSE.
// r14: half panel (128 cols = 4 tiles, 33KB LDS) -> per-wave barrier-free
// span halves (latency chains were the limiter, r13 post-mortem), LDS allows
// 4 blocks/CU so the VGPR-capped 2 resident blocks always have backfill,
// 2048 blocks = 8 rounds smooth the tail. One barrier; 2-acc pipeline.
// Frag-pair-major fp8: one ds_read_b128 = 2 k-step frags.

typedef float f32x4 __attribute__((ext_vector_type(4)));
typedef float f32x16 __attribute__((ext_vector_type(16)));
typedef long llong2 __attribute__((ext_vector_type(2)));

#define LN2F 0.6931471805599453f
#define LOG2EF 1.4426950408889634f
#define NB 8192
#define ND 256
#define NCHUNK 64   // column chunks; chunk = 128 cols = 4 tiles of 32

#define AS1 __attribute__((address_space(1)))
#define AS3 __attribute__((address_space(3)))

__device__ __forceinline__ float fexp2(float x) {
#if __has_builtin(__builtin_amdgcn_exp2f)
  return __builtin_amdgcn_exp2f(x);   // raw v_exp_f32
#else
  float r;
  asm("v_exp_f32 %0, %1\n\ts_nop 1" : "=v"(r) : "v"(x));
  return r;
#endif
}

__device__ __forceinline__ int pack4_fp8(float a, float b, float c, float d) {
#if __has_builtin(__builtin_amdgcn_cvt_pk_fp8_f32)
  int w = __builtin_amdgcn_cvt_pk_fp8_f32(a, b, 0, false);
  w = __builtin_amdgcn_cvt_pk_fp8_f32(c, d, w, true);
  return w;
#else
  unsigned b0 = __hip_fp8_e4m3(a).__x, b1 = __hip_fp8_e4m3(b).__x;
  unsigned b2 = __hip_fp8_e4m3(c).__x, b3 = __hip_fp8_e4m3(d).__x;
  return (int)(b0 | (b1 << 8) | (b2 << 16) | (b3 << 24));
#endif
}

// ---- kernel 1: convert to fp8 (P pre-scaled, 32x32 frag-pair layout) -----
// pos(k) = (k>>5)*32 + ((k>>3)&1)*16 + ((k>>4)&1)*8 + (k&7): a b128 read at
// t2*32 + hi*16 yields k-step frags (2*t2, hi) and (2*t2+1, hi) back-to-back.
__global__ __launch_bounds__(256) void vmse_prep(
    const float* __restrict__ pred, const float* __restrict__ gt,
    const float* __restrict__ sigma,
    unsigned char* __restrict__ Ah, unsigned char* __restrict__ Bh,
    float* __restrict__ diag, float* __restrict__ gnorm,
    float* __restrict__ ghs)
{
  const float nv = sigma[0] * sigma[0];
  const float s = LOG2EF / nv;
  const int row = blockIdx.x * 4 + (threadIdx.x >> 6);
  const int l = threadIdx.x & 63;
  const float4 p = *(const float4*)(pred + row * ND + l * 4);
  const float4 g = *(const float4*)(gt   + row * ND + l * 4);
  const int pw = pack4_fp8(p.x * s, p.y * s, p.z * s, p.w * s);
  const int gw = pack4_fp8(g.x, g.y, g.z, g.w);
  // lane l covers k = 4l..4l+3 (same 8-slice):
  const int pos = (l >> 3) * 32 + ((l >> 1) & 1) * 16 + ((l >> 2) & 1) * 8 + (l & 1) * 4;
  *(int*)(Ah + row * ND + pos) = pw;
  *(int*)(Bh + row * ND + pos) = gw;
  float dd = p.x * g.x + p.y * g.y + p.z * g.z + p.w * g.w;
  float gg = g.x * g.x + g.y * g.y + g.z * g.z + g.w * g.w;
  #pragma unroll
  for (int off = 1; off < 64; off <<= 1) {
    dd += __shfl_xor(dd, off);
    gg += __shfl_xor(gg, off);
  }
  if (l == 0) {
    diag[row] = dd;                // exact fp32 p_i . g_i
    gnorm[row] = gg;
    ghs[row] = -0.5f * s * gg;     // NEGATED base-2 logit offset (acc init)
  }
}

// online LSE over one acc's 16 base-2 logits
__device__ __forceinline__ void epi16(const f32x16& acc, float& m, float& l) {
  const float mx0 = fmaxf(fmaxf(acc[0], acc[1]), fmaxf(acc[2], acc[3]));
  const float mx1 = fmaxf(fmaxf(acc[4], acc[5]), fmaxf(acc[6], acc[7]));
  const float mx2 = fmaxf(fmaxf(acc[8], acc[9]), fmaxf(acc[10], acc[11]));
  const float mx3 = fmaxf(fmaxf(acc[12], acc[13]), fmaxf(acc[14], acc[15]));
  const float tmax = fmaxf(fmaxf(mx0, mx1), fmaxf(mx2, mx3));
  if (__any(tmax > m + 8.0f)) {      // T13 defer-max, rarely taken
    const float nm = fmaxf(m, tmax);
    l *= fexp2(m - nm);
    m = nm;
  }
  const float e0 = (fexp2(acc[0] - m) + fexp2(acc[1] - m)) +
                   (fexp2(acc[2] - m) + fexp2(acc[3] - m));
  const float e1 = (fexp2(acc[4] - m) + fexp2(acc[5] - m)) +
                   (fexp2(acc[6] - m) + fexp2(acc[7] - m));
  const float e2 = (fexp2(acc[8] - m) + fexp2(acc[9] - m)) +
                   (fexp2(acc[10] - m) + fexp2(acc[11] - m));
  const float e3 = (fexp2(acc[12] - m) + fexp2(acc[13] - m)) +
                   (fexp2(acc[14] - m) + fexp2(acc[15] - m));
  l += (e0 + e1) + (e2 + e3);
}

// ---- kernel 2: fused fp8 32x32 GEMM + online base-2 LSE, one-barrier -----
// grid 2048 = 32 row-blocks x 64 column chunks. 512 threads = 8 waves.
// LDS 33KB (4-tile panel) -> 4 blocks/CU LDS-wise; VGPR caps residency at 2
// but queued blocks backfill. Wave owns 32 pred rows (pf = 32 VGPR).
// G panel (4 tiles x 32 rows x 256B) staged via 4 global_load_lds/thread
// (linear dest; source chunk (l&15)^(r&7)). ONE __syncthreads, then 2-acc
// software pipeline: TILE(B,t+1) || epi(A,t) for VALU/MFMA co-issue.
// mfma(G,P): C/D col=lane&31 -> pred, row=(reg&3)+8*(reg>>2)+4*hi -> gt.
__global__ __launch_bounds__(512, 4) void vmse_main(
    const unsigned char* __restrict__ Ah, const unsigned char* __restrict__ Bh,
    const float* __restrict__ ghs, float* __restrict__ partial)
{
  __shared__ unsigned char lds[4][32 * 256];   // 32 KB: 128-col panel
  __shared__ float lds_ghs[128];               // chunk's (negated) offsets
  const int tid = threadIdx.x;
  const int lane = tid & 63;
  const int wid = tid >> 6;
  const int rb = blockIdx.x & 31;     // row block (256 rows)
  const int ch = blockIdx.x >> 5;     // column chunk (128 cols)
  const int r31 = lane & 31;
  const int hi = lane >> 5;
  const int j0 = ch * 128;

  // stage the whole 32KB panel: tile t -> lds[t]; 1 instr/thread/tile.
  {
    const int r = wid * 4 + (lane >> 4);
    const int cg = (lane & 15) ^ (r & 7);
    const unsigned char* src = Bh + (size_t)(j0 + r) * ND + cg * 16;
    #pragma unroll
    for (int t = 0; t < 4; ++t)
      __builtin_amdgcn_global_load_lds(
          (const AS1 unsigned int*)(src + t * 8192),
          (AS3 unsigned int*)&lds[t][wid * 1024], 16, 0, 0);
  }
  if (tid < 128) lds_ghs[tid] = ghs[j0 + tid];

  // P fragments (pre-scaled fp8): col = lane&31, k = hi*8+e per k-step.
  long pf[16];
  {
    const unsigned char* prow = Ah + (size_t)((rb * 256) + (wid * 32) + r31) * ND;
    #pragma unroll
    for (int t2 = 0; t2 < 8; ++t2) {
      const llong2 v = *(const llong2*)(prow + t2 * 32 + hi * 16);
      pf[2 * t2] = v[0];
      pf[2 * t2 + 1] = v[1];
    }
  }

  // quad-base LDS read pointers for the gt A-frags
  const int r0b = r31 & 1;
  const int q2 = (r31 >> 1) & 3;
  const char* base = (const char*)&lds[0][0] + r31 * 256 + (hi ^ r0b) * 16;
  const char* pq[4];
  #pragma unroll
  for (int b = 0; b < 4; ++b) pq[b] = base + ((b ^ q2) * 32);

  float m2 = -3.0e38f, l2 = 0.0f;

  __syncthreads();   // the ONLY barrier: panel + ghs resident

  const char* gbase = (const char*)lds_ghs + hi * 16;

  // one tile's acc-init + 16 MFMAs into a NAMED accumulator (rule #20)
  #define TILE(ACC, tile)                                                    \
    {                                                                        \
      _Pragma("unroll")                                                      \
      for (int q = 0; q < 4; ++q) {                                          \
        const f32x4 gv = *(const f32x4*)(gbase + (tile) * 128 + q * 32);     \
        ACC[4 * q + 0] = gv[0];                                              \
        ACC[4 * q + 1] = gv[1];                                              \
        ACC[4 * q + 2] = gv[2];                                              \
        ACC[4 * q + 3] = gv[3];                                              \
      }                                                                      \
      _Pragma("unroll")                                                      \
      for (int a = 0; a < 2; ++a) {                                          \
        _Pragma("unroll")                                                    \
        for (int b = 0; b < 4; ++b) {                                        \
          const llong2 g = *(const llong2*)(pq[b] + a * 128 + (tile) * 8192);\
          const int t = 2 * (a * 4 + b);                                     \
          ACC = __builtin_amdgcn_mfma_f32_32x32x16_fp8_fp8(g[0], pf[t], ACC, 0, 0, 0);     \
          ACC = __builtin_amdgcn_mfma_f32_32x32x16_fp8_fp8(g[1], pf[t + 1], ACC, 0, 0, 0); \
        }                                                                    \
      }                                                                      \
    }

  f32x16 accA, accB;
  TILE(accA, 0);
  TILE(accB, 1);
  epi16(accA, m2, l2);       // co-issues into accB's MFMA stream
  TILE(accA, 2);
  epi16(accB, m2, l2);
  TILE(accB, 3);
  epi16(accA, m2, l2);
  epi16(accB, m2, l2);

  // merge hi halves (same pred col, disjoint gt rows), write partial LSE
  {
    const float om = __shfl_xor(m2, 32);
    const float ol = __shfl_xor(l2, 32);
    const float nm = fmaxf(m2, om);
    l2 = l2 * fexp2(m2 - nm) + ol * fexp2(om - nm);
    m2 = nm;
    if (hi == 0) {
      const int row = rb * 256 + wid * 32 + r31;
      partial[row * NCHUNK + ch] = m2 + log2f(l2);
    }
  }
}

// ---- kernel 3: per-row combine of chunk partials + diagonal --------------
__global__ __launch_bounds__(256) void vmse_combine(
    const float* __restrict__ partial, const float* __restrict__ diag,
    const float* __restrict__ gnorm, const float* __restrict__ sigma,
    float* __restrict__ bsum)
{
  const int r = blockIdx.x * 256 + threadIdx.x;
  const float nv = sigma[0] * sigma[0];
  // online base-2 LSE over the 64 chunk partials (no register array)
  float m = -3.0e38f, l = 0.0f;
  #pragma unroll 8
  for (int c = 0; c < NCHUNK; ++c) {
    const float v = partial[r * NCHUNK + c];
    if (v > m) { l *= exp2f(m - v); m = v; }
    l += exp2f(v - m);
  }
  const float lse2 = m + log2f(l);             // base-2 LSE of z*log2e
  const float zii = (diag[r] - 0.5f * gnorm[r]) / nv;
  float contrib = LN2F * lse2 - zii;           // lse_e - z_ii
  #pragma unroll
  for (int off = 1; off < 64; off <<= 1) contrib += __shfl_xor(contrib, off);
  __shared__ float wsum[4];
  if ((threadIdx.x & 63) == 0) wsum[threadIdx.x >> 6] = contrib;
  __syncthreads();
  if (threadIdx.x == 0)
    bsum[blockIdx.x] = (wsum[0] + wsum[1]) + (wsum[2] + wsum[3]);
}

// ---- kernel 4: deterministic finalize ------------------------------------
__global__ __launch_bounds__(64) void vmse_final(
    const float* __restrict__ bsum, const float* __restrict__ sigma,
    float* __restrict__ out)
{
  const int lane = threadIdx.x;
  float v = (lane < 32) ? bsum[lane] : 0.f;
  #pragma unroll
  for (int off = 1; off < 64; off <<= 1) v += __shfl_xor(v, off);
  if (lane == 0) {
    const float nv = sigma[0] * sigma[0];
    out[0] = v * (2.0f * nv / (float)NB);
  }
}

extern "C" void kernel_launch(void* const* d_in, const int* in_sizes, int n_in,
                              void* d_out, int out_size, void* d_ws, size_t ws_size,
                              hipStream_t stream)
{
  const float* pred  = (const float*)d_in[0];
  const float* gt    = (const float*)d_in[1];
  const float* sigma = (const float*)d_in[2];
  char* ws = (char*)d_ws;
  // ws: Ah 2MB | Bh 2MB | gnorm 32KB | diag 32KB | ghs 32KB | partial 2MB | bsum
  unsigned char* Ah = (unsigned char*)(ws);
  unsigned char* Bh = (unsigned char*)(ws + (2u << 20));
  float* gnorm   = (float*)(ws + (4u << 20));
  float* diag    = (float*)(ws + (4u << 20) + (32u << 10));
  float* ghs     = (float*)(ws + (4u << 20) + (64u << 10));
  float* partial = (float*)(ws + (4u << 20) + (96u << 10));
  float* bsum    = (float*)(ws + (6u << 20) + (96u << 10));

  vmse_prep<<<NB / 4, 256, 0, stream>>>(pred, gt, sigma, Ah, Bh, diag, gnorm, ghs);
  vmse_main<<<32 * NCHUNK, 512, 0, stream>>>(Ah, Bh, ghs, partial);
  vmse_combine<<<NB / 256, 256, 0, stream>>>(partial, diag, gnorm, sigma, bsum);
  vmse_final<<<1, 64, 0, stream>>>(bsum, sigma, (float*)d_out);
}

// Round 15
// 38.304 us; speedup vs baseline: 1.3071x; 1.3071x over previous
//
#include <hip/hip_runtime.h>
#include <hip/hip_fp8.h>

// InfoNCE/contrastive MVN loss:
// loss = mean_i( LSE_j((p_i.g_j - 0.5|g_j|^2)/nv) - (p_i.g_i - 0.5|g_i|^2)/nv ) * 2nv
// B = 8192, D = 256, fp32 inputs, scalar fp32 output.
// r15: MX-scaled fp8 MFMA (mfma_scale_f32_32x32x64_f8f6f4, scales = 1.0):
// MFMA pipe 13.8 -> 7.3us (m59: 4686 TF), instruction count 1.05M -> 262K,
// acc chains 16 -> 4 per tile. K=64/instr makes A and B plain row-major 32B
// runs (no frag shuffle; identical lane->k packing for A and B so any HW
// k-permutation cancels). r13 geometry/schedule otherwise unchanged.

typedef float f32x4 __attribute__((ext_vector_type(4)));
typedef float f32x16 __attribute__((ext_vector_type(16)));
typedef int i32x4 __attribute__((ext_vector_type(4)));
typedef int i32x8 __attribute__((ext_vector_type(8)));

#define LN2F 0.6931471805599453f
#define LOG2EF 1.4426950408889634f
#define NB 8192
#define ND 256
#define NCHUNK 32   // column chunks; chunk = 256 cols = 8 tiles of 32

#define AS1 __attribute__((address_space(1)))
#define AS3 __attribute__((address_space(3)))

__device__ __forceinline__ float fexp2(float x) {
#if __has_builtin(__builtin_amdgcn_exp2f)
  return __builtin_amdgcn_exp2f(x);   // raw v_exp_f32
#else
  float r;
  asm("v_exp_f32 %0, %1\n\ts_nop 1" : "=v"(r) : "v"(x));
  return r;
#endif
}

__device__ __forceinline__ int pack4_fp8(float a, float b, float c, float d) {
#if __has_builtin(__builtin_amdgcn_cvt_pk_fp8_f32)
  int w = __builtin_amdgcn_cvt_pk_fp8_f32(a, b, 0, false);
  w = __builtin_amdgcn_cvt_pk_fp8_f32(c, d, w, true);
  return w;
#else
  unsigned b0 = __hip_fp8_e4m3(a).__x, b1 = __hip_fp8_e4m3(b).__x;
  unsigned b2 = __hip_fp8_e4m3(c).__x, b3 = __hip_fp8_e4m3(d).__x;
  return (int)(b0 | (b1 << 8) | (b2 << 16) | (b3 << 24));
#endif
}

// ---- kernel 1: convert to fp8 (P pre-scaled), PLAIN row-major layout -----
__global__ __launch_bounds__(256) void vmse_prep(
    const float* __restrict__ pred, const float* __restrict__ gt,
    const float* __restrict__ sigma,
    unsigned char* __restrict__ Ah, unsigned char* __restrict__ Bh,
    float* __restrict__ diag, float* __restrict__ gnorm,
    float* __restrict__ ghs)
{
  const float nv = sigma[0] * sigma[0];
  const float s = LOG2EF / nv;
  const int row = blockIdx.x * 4 + (threadIdx.x >> 6);
  const int l = threadIdx.x & 63;
  const float4 p = *(const float4*)(pred + row * ND + l * 4);
  const float4 g = *(const float4*)(gt   + row * ND + l * 4);
  const int pw = pack4_fp8(p.x * s, p.y * s, p.z * s, p.w * s);
  const int gw = pack4_fp8(g.x, g.y, g.z, g.w);
  *(int*)(Ah + row * ND + l * 4) = pw;    // byte k = element k
  *(int*)(Bh + row * ND + l * 4) = gw;
  float dd = p.x * g.x + p.y * g.y + p.z * g.z + p.w * g.w;
  float gg = g.x * g.x + g.y * g.y + g.z * g.z + g.w * g.w;
  #pragma unroll
  for (int off = 1; off < 64; off <<= 1) {
    dd += __shfl_xor(dd, off);
    gg += __shfl_xor(gg, off);
  }
  if (l == 0) {
    diag[row] = dd;                // exact fp32 p_i . g_i
    gnorm[row] = gg;
    ghs[row] = -0.5f * s * gg;     // NEGATED base-2 logit offset (acc init)
  }
}

// online LSE over one acc's 16 base-2 logits
__device__ __forceinline__ void epi16(const f32x16& acc, float& m, float& l) {
  const float mx0 = fmaxf(fmaxf(acc[0], acc[1]), fmaxf(acc[2], acc[3]));
  const float mx1 = fmaxf(fmaxf(acc[4], acc[5]), fmaxf(acc[6], acc[7]));
  const float mx2 = fmaxf(fmaxf(acc[8], acc[9]), fmaxf(acc[10], acc[11]));
  const float mx3 = fmaxf(fmaxf(acc[12], acc[13]), fmaxf(acc[14], acc[15]));
  const float tmax = fmaxf(fmaxf(mx0, mx1), fmaxf(mx2, mx3));
  if (__any(tmax > m + 8.0f)) {      // T13 defer-max, rarely taken
    const float nm = fmaxf(m, tmax);
    l *= fexp2(m - nm);
    m = nm;
  }
  const float e0 = (fexp2(acc[0] - m) + fexp2(acc[1] - m)) +
                   (fexp2(acc[2] - m) + fexp2(acc[3] - m));
  const float e1 = (fexp2(acc[4] - m) + fexp2(acc[5] - m)) +
                   (fexp2(acc[6] - m) + fexp2(acc[7] - m));
  const float e2 = (fexp2(acc[8] - m) + fexp2(acc[9] - m)) +
                   (fexp2(acc[10] - m) + fexp2(acc[11] - m));
  const float e3 = (fexp2(acc[12] - m) + fexp2(acc[13] - m)) +
                   (fexp2(acc[14] - m) + fexp2(acc[15] - m));
  l += (e0 + e1) + (e2 + e3);
}

// ---- kernel 2: fused MX-fp8 32x32x64 GEMM + online LSE, one-barrier ------
// grid 1024 = 32 row-blocks x 32 column chunks. 512 threads = 8 waves,
// 2 blocks/CU (65KB LDS). Wave owns 32 pred rows. G panel (8 tiles x 32 rows
// x 256B) staged via 8 global_load_lds/thread; LDS 16B-chunk swizzle: chunk
// c of row r holds global chunk c^(r&15) (bank-balanced for the stride-256B
// b128 reads). ONE __syncthreads, then per tile: 4 scale-MFMAs (K=64) per
// acc; 2-acc pipeline interleaves epi(t) with MFMA(t+1).
// A-frag (G): lane = row l&31, k = (l>>5)*32 + 0..31 -> 2 b128 at chunks
// (m*4 + hi*2 + j) ^ (r&15); dual x quad base pointers make all hot-loop
// addresses compile-time immediates. B-frag (P): same packing -> cancels.
// C/D: col = lane&31 -> pred, row = (reg&3)+8*(reg>>2)+4*hi -> gt.
__global__ __launch_bounds__(512, 4) void vmse_main(
    const unsigned char* __restrict__ Ah, const unsigned char* __restrict__ Bh,
    const float* __restrict__ ghs, float* __restrict__ partial)
{
  __shared__ unsigned char lds[8][32 * 256];   // 64 KB: whole column chunk
  __shared__ float lds_ghs[256];               // chunk's (negated) offsets
  const int tid = threadIdx.x;
  const int lane = tid & 63;
  const int wid = tid >> 6;
  const int rb = blockIdx.x & 31;     // row block (256 rows)
  const int ch = blockIdx.x >> 5;     // column chunk (256 cols)
  const int r31 = lane & 31;
  const int hi = lane >> 5;
  const int j0 = ch * 256;

  // stage the whole 64KB panel: tile t -> lds[t]; 1 instr/thread/tile.
  // lane l: row r = wid*4 + (l>>4); source chunk (l&15)^(r&15); dest linear.
  {
    const int r = wid * 4 + (lane >> 4);
    const int cg = (lane & 15) ^ (r & 15);
    const unsigned char* src = Bh + (size_t)(j0 + r) * ND + cg * 16;
    #pragma unroll
    for (int t = 0; t < 8; ++t)
      __builtin_amdgcn_global_load_lds(
          (const AS1 unsigned int*)(src + t * 8192),
          (AS3 unsigned int*)&lds[t][wid * 1024], 16, 0, 0);
  }
  if (tid < 256) lds_ghs[tid] = ghs[j0 + tid];

  // P fragments (pre-scaled fp8, plain row-major): col = lane&31,
  // k = hi*32 + 0..31 per K-window m. 4 x i32x8 = 32 VGPR.
  i32x8 pf[4];
  {
    const unsigned char* prow = Ah + (size_t)((rb * 256) + (wid * 32) + r31) * ND;
    #pragma unroll
    for (int m = 0; m < 4; ++m)
      pf[m] = *(const i32x8*)(prow + m * 64 + hi * 32);
  }

  // dual x quad base pointers for the G A-frags:
  // addr(m,j) = r31*256 + ((m*4 + hi*2 + j) ^ (r31&15))*16
  //           = [r31*256 + ((hi*2+j)^sl)*16] + ((m^sh)<<6)
  const int sl = r31 & 3;
  const int sh = (r31 >> 2) & 3;
  const char* ldsc = (const char*)&lds[0][0];
  const char* pj0 = ldsc + r31 * 256 + (((hi * 2) ^ sl) * 16);
  const char* pj1 = ldsc + r31 * 256 + (((hi * 2 + 1) ^ sl) * 16);
  const char* pg0[4];
  const char* pg1[4];
  #pragma unroll
  for (int m = 0; m < 4; ++m) {
    pg0[m] = pj0 + ((m ^ sh) << 6);
    pg1[m] = pj1 + ((m ^ sh) << 6);
  }

  float m2 = -3.0e38f, l2 = 0.0f;

  __syncthreads();   // the ONLY barrier: panel + ghs resident

  const char* gbase = (const char*)lds_ghs + hi * 16;

  // one tile: ghs acc-init + 4 chained K=64 scale-MFMAs (scales = 1.0)
  #define TILE(ACC, tile)                                                    \
    {                                                                        \
      _Pragma("unroll")                                                      \
      for (int q = 0; q < 4; ++q) {                                          \
        const f32x4 gv = *(const f32x4*)(gbase + (tile) * 128 + q * 32);     \
        ACC[4 * q + 0] = gv[0];                                              \
        ACC[4 * q + 1] = gv[1];                                              \
        ACC[4 * q + 2] = gv[2];                                              \
        ACC[4 * q + 3] = gv[3];                                              \
      }                                                                      \
      _Pragma("unroll")                                                      \
      for (int m = 0; m < 4; ++m) {                                          \
        const i32x4 a0 = *(const i32x4*)(pg0[m] + (tile) * 8192);            \
        const i32x4 a1 = *(const i32x4*)(pg1[m] + (tile) * 8192);            \
        const i32x8 ga = {a0[0], a0[1], a0[2], a0[3],                        \
                          a1[0], a1[1], a1[2], a1[3]};                       \
        ACC = __builtin_amdgcn_mfma_scale_f32_32x32x64_f8f6f4(               \
            ga, pf[m], ACC, 0, 0, 0, 0x7F7F7F7F, 0, 0x7F7F7F7F);             \
      }                                                                      \
    }

  f32x16 accA, accB;
  TILE(accA, 0);
  #pragma unroll
  for (int i = 0; i < 4; ++i) {
    TILE(accB, 2 * i + 1);     // MFMA stream (independent of accA)
    epi16(accA, m2, l2);       // VALU+trans, co-issues into MFMA gaps
    if (2 * i + 2 < 8) {
      TILE(accA, 2 * i + 2);
    }
    epi16(accB, m2, l2);
  }

  // merge hi halves (same pred col, disjoint gt rows), write partial LSE
  {
    const float om = __shfl_xor(m2, 32);
    const float ol = __shfl_xor(l2, 32);
    const float nm = fmaxf(m2, om);
    l2 = l2 * fexp2(m2 - nm) + ol * fexp2(om - nm);
    m2 = nm;
    if (hi == 0) {
      const int row = rb * 256 + wid * 32 + r31;
      partial[row * NCHUNK + ch] = m2 + log2f(l2);
    }
  }
}

// ---- kernel 3: per-row combine of chunk partials + diagonal --------------
__global__ __launch_bounds__(256) void vmse_combine(
    const float* __restrict__ partial, const float* __restrict__ diag,
    const float* __restrict__ gnorm, const float* __restrict__ sigma,
    float* __restrict__ bsum)
{
  const int r = blockIdx.x * 256 + threadIdx.x;
  const float nv = sigma[0] * sigma[0];
  float p[NCHUNK];
  float M = -3.0e38f;
  #pragma unroll
  for (int c = 0; c < NCHUNK; ++c) { p[c] = partial[r * NCHUNK + c]; M = fmaxf(M, p[c]); }
  float ssum = 0.f;
  #pragma unroll
  for (int c = 0; c < NCHUNK; ++c) ssum += exp2f(p[c] - M);
  const float lse2 = M + log2f(ssum);          // base-2 LSE of z*log2e
  const float zii = (diag[r] - 0.5f * gnorm[r]) / nv;
  float contrib = LN2F * lse2 - zii;           // lse_e - z_ii
  #pragma unroll
  for (int off = 1; off < 64; off <<= 1) contrib += __shfl_xor(contrib, off);
  __shared__ float wsum[4];
  if ((threadIdx.x & 63) == 0) wsum[threadIdx.x >> 6] = contrib;
  __syncthreads();
  if (threadIdx.x == 0)
    bsum[blockIdx.x] = (wsum[0] + wsum[1]) + (wsum[2] + wsum[3]);
}

// ---- kernel 4: deterministic finalize ------------------------------------
__global__ __launch_bounds__(64) void vmse_final(
    const float* __restrict__ bsum, const float* __restrict__ sigma,
    float* __restrict__ out)
{
  const int lane = threadIdx.x;
  float v = (lane < 32) ? bsum[lane] : 0.f;
  #pragma unroll
  for (int off = 1; off < 64; off <<= 1) v += __shfl_xor(v, off);
  if (lane == 0) {
    const float nv = sigma[0] * sigma[0];
    out[0] = v * (2.0f * nv / (float)NB);
  }
}

extern "C" void kernel_launch(void* const* d_in, const int* in_sizes, int n_in,
                              void* d_out, int out_size, void* d_ws, size_t ws_size,
                              hipStream_t stream)
{
  const float* pred  = (const float*)d_in[0];
  const float* gt    = (const float*)d_in[1];
  const float* sigma = (const float*)d_in[2];
  char* ws = (char*)d_ws;
  // ws: Ah 2MB | Bh 2MB | gnorm 32KB | diag 32KB | ghs 32KB | partial 1MB | bsum
  unsigned char* Ah = (unsigned char*)(ws);
  unsigned char* Bh = (unsigned char*)(ws + (2u << 20));
  float* gnorm   = (float*)(ws + (4u << 20));
  float* diag    = (float*)(ws + (4u << 20) + (32u << 10));
  float* ghs     = (float*)(ws + (4u << 20) + (64u << 10));
  float* partial = (float*)(ws + (4u << 20) + (96u << 10));
  float* bsum    = (float*)(ws + (4u << 20) + (96u << 10) + (1u << 20));

  vmse_prep<<<NB / 4, 256, 0, stream>>>(pred, gt, sigma, Ah, Bh, diag, gnorm, ghs);
  vmse_main<<<32 * NCHUNK, 512, 0, stream>>>(Ah, Bh, ghs, partial);
  vmse_combine<<<NB / 256, 256, 0, stream>>>(partial, diag, gnorm, sigma, bsum);
  vmse_final<<<1, 64, 0, stream>>>(bsum, sigma, (float*)d_out);
}